// Round 2
// baseline (478.981 us; speedup 1.0000x reference)
//
#include <hip/hip_runtime.h>
#include <stdint.h>

#define TT 2048
#define BB 4
#define HH 768
#define NHEADS 4
#define DD 768
#define NN 3072   // NHEADS*DD
#define LL 3
#define BT 8192   // BB*TT
#define KNB 5

typedef __bf16 bf16x8 __attribute__((ext_vector_type(8)));
typedef float f32x4 __attribute__((ext_vector_type(4)));

__device__ __forceinline__ unsigned short f2bf(float f){
  union { float f; unsigned u; } v; v.f = f;
  unsigned u = v.u;
  return (unsigned short)((u + 0x7FFFu + ((u >> 16) & 1u)) >> 16);
}
__device__ __forceinline__ float bf2f(unsigned short h){
  union { unsigned u; float f; } v; v.u = ((unsigned)h) << 16;
  return v.f;
}

// ---------------- W transpose + bf16 convert: W[l][k][n] fp32 -> Wt[l][n][k] bf16
__global__ void wt_kernel(const float* __restrict__ W, unsigned short* __restrict__ Wt){
  __shared__ float tile[32][33];
  int l = blockIdx.z;
  int n0 = blockIdx.x * 32, k0 = blockIdx.y * 32;
  int tx = threadIdx.x, ty = threadIdx.y; // (32,8)
  const float* Wl = W + (size_t)l * HH * NN;
  for (int r = 0; r < 4; r++)
    tile[ty + r*8][tx] = Wl[(size_t)(k0 + ty + r*8) * NN + n0 + tx];
  __syncthreads();
  unsigned short* Wtl = Wt + (size_t)l * NN * HH;
  for (int r = 0; r < 4; r++){
    int n = n0 + ty + r*8;
    Wtl[(size_t)n * HH + k0 + tx] = f2bf(tile[tx][ty + r*8]);
  }
}

// ---------------- x fp32 -> bf16
__global__ void xconv_kernel(const float* __restrict__ x, unsigned short* __restrict__ xb){
  int i = blockIdx.x * blockDim.x + threadIdx.x; // 4 elems per thread
  float4 v = ((const float4*)x)[i];
  ushort4 o;
  o.x = f2bf(v.x); o.y = f2bf(v.y); o.z = f2bf(v.z); o.w = f2bf(v.w);
  *(ushort4*)(xb + (size_t)i * 4) = o;
}

// ---------------- GEMM: h[BT][NN] bf16 = xb[BT][HH] * Wt^T (Wt is [NN][HH])
#define BM 128
#define BN 128
#define BK 32
#define PAD 40

__global__ __launch_bounds__(256, 2) void gemm_kernel(
    const unsigned short* __restrict__ xb,
    const unsigned short* __restrict__ wt,
    unsigned short* __restrict__ hout){
  __shared__ unsigned short xs[BM][PAD];
  __shared__ unsigned short wsd[BN][PAD];
  int bm = blockIdx.y * BM;
  int bn = blockIdx.x * BN;
  int tid = threadIdx.x;
  int wave = tid >> 6, lane = tid & 63;
  int m16 = lane & 15, q = lane >> 4;
  int wm = (wave >> 1) * 64, wn = (wave & 1) * 64;
  // staging: 256 threads cover 128 rows x 32 cols (bf16) per tile;
  // each thread stages TWO rows (srow, srow+64) x 8 cols. (R1 bugfix:
  // previously only rows 0..63 were staged -> NaN from stale LDS.)
  int srow = tid >> 2, scol = (tid & 3) * 8;
  const unsigned short* xg  = xb + (size_t)(bm + srow) * HH + scol;
  const unsigned short* xg2 = xb + (size_t)(bm + srow + 64) * HH + scol;
  const unsigned short* wg  = wt + (size_t)(bn + srow) * HH + scol;
  const unsigned short* wg2 = wt + (size_t)(bn + srow + 64) * HH + scol;
  f32x4 acc[4][4] = {};
  for (int k0 = 0; k0 < HH; k0 += BK){
    uint4 xv  = *(const uint4*)(xg + k0);
    uint4 xv2 = *(const uint4*)(xg2 + k0);
    uint4 wv  = *(const uint4*)(wg + k0);
    uint4 wv2 = *(const uint4*)(wg2 + k0);
    *(uint4*)(&xs[srow][scol])        = xv;
    *(uint4*)(&xs[srow + 64][scol])   = xv2;
    *(uint4*)(&wsd[srow][scol])       = wv;
    *(uint4*)(&wsd[srow + 64][scol])  = wv2;
    __syncthreads();
    bf16x8 af[4], bfr[4];
    for (int i = 0; i < 4; i++)
      af[i] = __builtin_bit_cast(bf16x8, *(const uint4*)(&xs[wm + i*16 + m16][q*8]));
    for (int j = 0; j < 4; j++)
      bfr[j] = __builtin_bit_cast(bf16x8, *(const uint4*)(&wsd[wn + j*16 + m16][q*8]));
    for (int i = 0; i < 4; i++)
      for (int j = 0; j < 4; j++)
        acc[i][j] = __builtin_amdgcn_mfma_f32_16x16x32_bf16(af[i], bfr[j], acc[i][j], 0, 0, 0);
    __syncthreads();
  }
  for (int i = 0; i < 4; i++){
    int row0 = bm + wm + i*16 + q*4;
    for (int j = 0; j < 4; j++){
      int col = bn + wn + j*16 + m16;
      unsigned short* hp = hout + (size_t)row0 * NN + col;
      hp[0]            = f2bf(acc[i][j][0]);
      hp[NN]           = f2bf(acc[i][j][1]);
      hp[2*(size_t)NN] = f2bf(acc[i][j][2]);
      hp[3*(size_t)NN] = f2bf(acc[i][j][3]);
    }
  }
}

// ---------------- asrc/adst: per (token,head) dot of h row-chunk with a_src/a_dst
__global__ __launch_bounds__(256) void srcdst_kernel(const unsigned short* __restrict__ h,
      const float* __restrict__ asrc_w, const float* __restrict__ adst_w,
      float* __restrict__ asrc, float* __restrict__ adst){
  int tid = threadIdx.x;
  int wave = tid >> 6, lane = tid & 63;
  int task = blockIdx.x * 4 + wave; // token*4 + head
  int token = task >> 2, head = task & 3;
  const unsigned short* hrow = h + (size_t)token * NN + head * DD;
  const float* sw = asrc_w + head * DD;
  const float* dw = adst_w + head * DD;
  float ssum = 0.f, dsum = 0.f;
  for (int i = 0; i < 12; i++){
    int c = i * 64 + lane;
    float hv = bf2f(hrow[c]);
    ssum += hv * sw[c];
    dsum += hv * dw[c];
  }
  for (int off = 32; off > 0; off >>= 1){
    ssum += __shfl_xor(ssum, off, 64);
    dsum += __shfl_xor(dsum, off, 64);
  }
  if (lane == 0){
    asrc[task] = ssum;
    adst[task] = dsum;
  }
}

// ---------------- attention + head-mean + bias + residual + layernorm
__global__ __launch_bounds__(256) void attn_ln_kernel(const unsigned short* __restrict__ h,
    const float* __restrict__ asrc, const float* __restrict__ adst,
    const float* __restrict__ x_in, const float* __restrict__ bias_l,
    const float* __restrict__ gamma_l, const float* __restrict__ beta_l,
    float* __restrict__ x_out){
  int token = blockIdx.x;          // b*TT + t
  int t = token & (TT - 1);
  int tid = threadIdx.x;
  __shared__ float attn_s[NHEADS][KNB];
  __shared__ float rs[4], rq[4];
  if (tid < NHEADS){
    int head = tid;
    float sc[KNB];
    float mx = -3.0e38f;
    float ad = adst[token * NHEADS + head];
    for (int k = 0; k < KNB; k++){
      int tn = t + k - 2;
      if (tn >= 0 && tn < TT){
        float s = asrc[(token + k - 2) * NHEADS + head] + ad;
        s = s > 0.f ? s : 0.2f * s;       // leaky_relu 0.2
        sc[k] = s; mx = fmaxf(mx, s);
      } else sc[k] = -3.0e38f;
    }
    float den = 0.f;
    for (int k = 0; k < KNB; k++){
      float e = (sc[k] > -1.0e38f) ? __expf(sc[k] - mx) : 0.f;
      sc[k] = e; den += e;
    }
    float inv = 0.25f / den;              // fold 1/HEADS into attn
    for (int k = 0; k < KNB; k++) attn_s[head][k] = sc[k] * inv;
  }
  __syncthreads();
  float areg[NHEADS][KNB];
  for (int hd = 0; hd < NHEADS; hd++)
    for (int k = 0; k < KNB; k++) areg[hd][k] = attn_s[hd][k];
  float z[3]; float sum = 0.f, sumsq = 0.f;
  const size_t base = (size_t)token * NN;
  for (int r = 0; r < 3; r++){
    int d = tid + r * 256;
    float y = 0.f;
    for (int k = 0; k < KNB; k++){
      int tn = t + k - 2;
      if (tn < 0 || tn >= TT) continue;   // wave-uniform branch (t uniform per block)
      const unsigned short* hrow = h + base + (long long)(k - 2) * NN + d;
      y += areg[0][k] * bf2f(hrow[0]);
      y += areg[1][k] * bf2f(hrow[DD]);
      y += areg[2][k] * bf2f(hrow[2*DD]);
      y += areg[3][k] * bf2f(hrow[3*DD]);
    }
    float zz = y + bias_l[d] + x_in[(size_t)token * HH + d];
    z[r] = zz; sum += zz; sumsq += zz * zz;
  }
  int wave = tid >> 6, lane = tid & 63;
  for (int off = 32; off > 0; off >>= 1){
    sum += __shfl_xor(sum, off, 64);
    sumsq += __shfl_xor(sumsq, off, 64);
  }
  if (lane == 0){ rs[wave] = sum; rq[wave] = sumsq; }
  __syncthreads();
  float ts = rs[0] + rs[1] + rs[2] + rs[3];
  float tq = rq[0] + rq[1] + rq[2] + rq[3];
  float mean = ts * (1.f / HH);
  float var = tq * (1.f / HH) - mean * mean;
  float rstd = rsqrtf(var + 1e-5f);
  for (int r = 0; r < 3; r++){
    int d = tid + r * 256;
    x_out[(size_t)token * HH + d] = (z[r] - mean) * rstd * gamma_l[d] + beta_l[d];
  }
}

extern "C" void kernel_launch(void* const* d_in, const int* in_sizes, int n_in,
                              void* d_out, int out_size, void* d_ws, size_t ws_size,
                              hipStream_t stream) {
  const float* x     = (const float*)d_in[0];
  const float* W     = (const float*)d_in[1];
  const float* a_src = (const float*)d_in[2];
  const float* a_dst = (const float*)d_in[3];
  const float* bias  = (const float*)d_in[4];
  const float* gamma = (const float*)d_in[5];
  const float* beta  = (const float*)d_in[6];
  float* out = (float*)d_out;

  char* ws = (char*)d_ws;
  size_t off = 0;
  auto alloc = [&](size_t bytes)->char*{
    char* p = ws + off;
    off = (off + bytes + 255) & ~(size_t)255;
    return p;
  };
  unsigned short* wt   = (unsigned short*)alloc((size_t)LL * NN * HH * 2);
  unsigned short* xb   = (unsigned short*)alloc((size_t)BT * HH * 2);
  unsigned short* hbuf = (unsigned short*)alloc((size_t)BT * NN * 2);
  float* asrcb = (float*)alloc((size_t)BT * NHEADS * 4);
  float* adstb = (float*)alloc((size_t)BT * NHEADS * 4);

  // transpose+convert all layer weights once
  wt_kernel<<<dim3(NN/32, HH/32, LL), dim3(32, 8), 0, stream>>>(W, wt);

  for (int l = 0; l < LL; l++){
    const float* xin = (l == 0) ? x : out;
    xconv_kernel<<<(BT * HH / 4) / 256, 256, 0, stream>>>(xin, xb);
    gemm_kernel<<<dim3(NN / BN, BT / BM), 256, 0, stream>>>(xb, wt + (size_t)l * NN * HH, hbuf);
    srcdst_kernel<<<BT * NHEADS / 4, 256, 0, stream>>>(hbuf,
        a_src + (size_t)l * NHEADS * DD, a_dst + (size_t)l * NHEADS * DD, asrcb, adstb);
    attn_ln_kernel<<<BT, 256, 0, stream>>>(hbuf, asrcb, adstb, xin,
        bias + (size_t)l * DD, gamma + (size_t)l * HH, beta + (size_t)l * HH, out);
  }
}